// Round 15
// baseline (282.749 us; speedup 1.0000x reference)
//
#include <hip/hip_runtime.h>
#include <hip/hip_bf16.h>

#define ACT 14
#define CC 128
#define HH 256
#define EPB 182                 // edges per batch (14*13)
#define NB 2048
#define M2 (NB*EPB)             // 372736 edge-rows
#define NS 520                  // nodeL stride in shorts
#define LP_CONST (-182.0f * 0.91893853320467274f)   // -E*0.5*ln(2pi)

typedef short s16x8 __attribute__((ext_vector_type(8)));
typedef float f32x4 __attribute__((ext_vector_type(4)));

__device__ __forceinline__ short f2bf(float f) {
    unsigned u = __float_as_uint(f);
    unsigned r = (u + 0x7fffu + ((u >> 16) & 1u)) >> 16;   // RNE
    return (short)r;
}
__device__ __forceinline__ float bflo(int m) { return __uint_as_float(((unsigned)m) << 16); }
__device__ __forceinline__ float bfhi(int m) { return __uint_as_float((unsigned)m & 0xffff0000u); }
__device__ __forceinline__ float leaky(float x) { return fmaxf(x, 0.01f * x); }
__device__ __forceinline__ float softplusf(float x) { return x > 15.f ? x : log1pf(expf(x)); }

union bf2u { __hip_bfloat162 h; int i; };
__device__ __forceinline__ int pk_bf16(float a, float b) {
    bf2u u; u.h = __float22bfloat162_rn(make_float2(a, b));
    return u.i;
}

// ---------------------------------------------------------------------------
// prep: bf16 weight conversions only (256 blocks x 256)
// ---------------------------------------------------------------------------
__global__ __launch_bounds__(256) void prep_kernel(
    const float* __restrict__ lin1_w, const float* __restrict__ lin2_w,
    short* __restrict__ W2bf, short* __restrict__ W1bf)
{
    int i = blockIdx.x * 256 + threadIdx.x;
    W2bf[i] = f2bf(lin2_w[i]);
    int n = i >> 7, k = i & 127;
    float v = (n < 256) ? lin1_w[n * 256 + k] : lin1_w[(n - 256) * 256 + 128 + k];
    W1bf[i] = f2bf(v);
}

// ---------------------------------------------------------------------------
// actor: TWO batches per block (1024 blocks), 1024 threads = 16 waves.
// Phase C: 16x16x32 MFMA; each wave owns a 16-row W2 strip (wa[8] = 32 regs,
// acc = 8 regs) -> fits 64-reg cap -> 2 blocks x 16 waves = 32 waves/CU.
// h1L frag-order double buffer; build = 1 linear slot per thread.
// ---------------------------------------------------------------------------
__global__ __launch_bounds__(1024, 8) void actor_kernel(
    const float* __restrict__ state, const float* __restrict__ conv_w,
    const float* __restrict__ conv_b, const float* __restrict__ lin1_w,
    const float* __restrict__ lin1_b, const short* __restrict__ W1bf,
    const short* __restrict__ W2bf, const float* __restrict__ lin2_b,
    const float* __restrict__ mu_w, const float* __restrict__ mu_b,
    const float* __restrict__ sig_w, const float* __restrict__ sig_b,
    const float* __restrict__ noise, const int* __restrict__ edges,
    float* __restrict__ out)
{
    __shared__ short h1L[2][8192];           // 32 KB; fronts aliased below
    __shared__ short nodeL[2 * ACT * NS];    // 29120 B
    __shared__ float wL[2][256];
    __shared__ float b2L[256], muL[256], sgL[256];
    __shared__ float mu_acc[384], sg_acc[384];
    __shared__ float lp_acc[2];

    short* stateL = &h1L[0][0];              // 2*2560 shorts (dead before tiles)
    float* pp     = (float*)&h1L[0][5120];   // 1024 f32 partials (dead before tiles)
    float* ssumLp = (float*)&h1L[1][0];      // 2*128 f32 (dead before tiles)
    float* gLp    = (float*)&h1L[1][512];    // 2*128 f32 (dead before tiles)

    const int t = threadIdx.x, b = blockIdx.x;
    const int lane = t & 63, ln = lane & 15, q = lane >> 4;
    const int w = t >> 6;                     // wave 0..15

    // ---- phase A: stage state bf16 (1024 slots), tables, ssum ----
    {
        int bt = t >> 9, row = (t >> 5) & 15, c4 = t & 31;
        int kk = c4 >> 3, k8 = (c4 & 7) * 4;
        int* dst = (int*)&stateL[bt * 2560 + kk * 640 + row * 40 + k8];
        if (row < ACT) {
            f32x4 x = *(const f32x4*)(state + ((size_t)(2 * b + bt) * ACT + row) * CC + c4 * 4);
            dst[0] = pk_bf16(x[0], x[1]); dst[1] = pk_bf16(x[2], x[3]);
        } else { dst[0] = 0; dst[1] = 0; }
    }
    if (t < 256) {
        b2L[t] = lin2_b[t]; muL[t] = mu_w[t]; sgL[t] = sig_w[t];
    } else if (t < 512) {
        int i = t - 256, bt = i >> 7, c = i & 127;    // ssum, both batches
        const float* sp = state + (size_t)(2 * b + bt) * ACT * CC + c;
        float s = 0.f;
        #pragma unroll
        for (int r = 0; r < ACT; ++r) s += sp[r * CC];
        ssumLp[bt * 128 + c] = s * (1.f / 14.f);
    }
    if (t < 384) { mu_acc[t] = 0.f; sg_acc[t] = 0.f; }
    if (t < 2) lp_acc[t] = 0.f;
    __syncthreads();

    // ---- A2: g partials, 4-way k-split over all 1024 threads ----
    {
        int bt = t >> 9, s = (t >> 7) & 3, j = t & 127;
        const float* cw = conv_w + j * CC + s * 32;
        const float* ss = ssumLp + bt * 128 + s * 32;
        float a0 = 0.f, a1 = 0.f, a2 = 0.f, a3 = 0.f;
        #pragma unroll
        for (int c4 = 0; c4 < 32; c4 += 4) {
            f32x4 wv = *(const f32x4*)(cw + c4);
            f32x4 sv = *(const f32x4*)(ss + c4);
            a0 += wv[0] * sv[0]; a1 += wv[1] * sv[1];
            a2 += wv[2] * sv[2]; a3 += wv[3] * sv[3];
        }
        pp[t] = (a0 + a1) + (a2 + a3);
    }
    __syncthreads();
    if (t < 256) {
        int bt = t >> 7, j = t & 127;
        float a = pp[bt * 512 + j] + pp[bt * 512 + 128 + j]
                + pp[bt * 512 + 256 + j] + pp[bt * 512 + 384 + j] + conv_b[j];
        gLp[bt * 128 + j] = fmaxf(a, 0.f);
    }
    __syncthreads();
    // ---- w partials: 2-way k-split over all 1024 threads ----
    {
        int bt = t >> 9, s = (t >> 8) & 1, h = t & 255;
        const float* w1 = lin1_w + (size_t)h * 256 + s * 64;
        const float* gg = gLp + bt * 128 + s * 64;
        float a0 = 0.f, a1 = 0.f, a2 = 0.f, a3 = 0.f;
        #pragma unroll
        for (int c4 = 0; c4 < 64; c4 += 4) {
            f32x4 wl = *(const f32x4*)(w1 + c4);
            f32x4 wr = *(const f32x4*)(w1 + 128 + c4);
            f32x4 gv = *(const f32x4*)(gg + c4);
            a0 += (wl[0] + wr[0]) * gv[0]; a1 += (wl[1] + wr[1]) * gv[1];
            a2 += (wl[2] + wr[2]) * gv[2]; a3 += (wl[3] + wr[3]) * gv[3];
        }
        pp[t] = (a0 + a1) + (a2 + a3);
    }
    __syncthreads();
    if (t < 512) {
        int bt = t >> 8, h = t & 255;
        wL[bt][h] = pp[bt * 512 + h] + pp[bt * 512 + 256 + h] + lin1_b[h];
    }
    __syncthreads();

    // ---- phase B: node GEMM (u = W1L@x + w | v = W1R@x), 16 waves x 16 cols x2 ----
    f32x4 zero4 = {0.f, 0.f, 0.f, 0.f};
    f32x4 nacc[2][2];
    nacc[0][0] = zero4; nacc[0][1] = zero4;
    nacc[1][0] = zero4; nacc[1][1] = zero4;
    #pragma unroll
    for (int c = 0; c < 4; ++c) {
        s16x8 a80 = *(const s16x8*)&stateL[0 * 2560 + c * 640 + ln * 40 + q * 8];
        s16x8 a81 = *(const s16x8*)&stateL[1 * 2560 + c * 640 + ln * 40 + q * 8];
        #pragma unroll
        for (int i = 0; i < 2; ++i) {
            int n = i * 256 + w * 16 + ln;
            s16x8 b8 = *(const s16x8*)&W1bf[(size_t)n * CC + c * 32 + q * 8];
            nacc[0][i] = __builtin_amdgcn_mfma_f32_16x16x32_bf16(a80, b8, nacc[0][i], 0, 0, 0);
            nacc[1][i] = __builtin_amdgcn_mfma_f32_16x16x32_bf16(a81, b8, nacc[1][i], 0, 0, 0);
        }
    }
    #pragma unroll
    for (int bt = 0; bt < 2; ++bt)
        #pragma unroll
        for (int i = 0; i < 2; ++i) {
            int col = w * 16 + ln;
            float wadd = (i == 0) ? wL[bt][col] : 0.f;
            #pragma unroll
            for (int rg = 0; rg < 4; ++rg) {
                int node = q * 4 + rg;
                if (node < ACT)
                    nodeL[(bt * ACT + node) * NS + i * 256 + col] = f2bf(nacc[bt][i][rg] + wadd);
            }
        }

    // ---- W2 strip: 16 rows x K=256 -> wa[8] (32 regs) ----
    s16x8 wa[8];
    #pragma unroll
    for (int c = 0; c < 8; ++c)
        wa[c] = *(const s16x8*)&W2bf[(size_t)(w * 16 + ln) * HH + c * 32 + q * 8];
    __syncthreads();   // nodeL visible; stateL/pp/ssum/g dead

    // cooperative H1 build: 1 slot per thread, dst perfectly linear
    auto build = [&](int tile, int bufi) {
        int bt = (tile >= 6) ? 1 : 0;
        int e = (tile - bt * 6) * 32 + (t & 31);
        int slot8 = (t >> 5) * 8;              // k offset 0..248
        int o[4] = {0, 0, 0, 0};
        if (e < EPB) {
            int2 p = ((const int2*)edges)[e];
            int base = bt * ACT * NS;
            s16x8 u8 = *(const s16x8*)&nodeL[base + p.x * NS + slot8];
            s16x8 v8 = *(const s16x8*)&nodeL[base + HH + p.y * NS + slot8];
            const int* ui = (const int*)&u8;
            const int* vi = (const int*)&v8;
            #pragma unroll
            for (int j = 0; j < 4; ++j) {
                int uu = ui[j], vv = vi[j];
                float s0 = bflo(uu) + bflo(vv);
                float s1 = bfhi(uu) + bfhi(vv);
                o[j] = pk_bf16(leaky(s0), leaky(s1));
            }
        }
        *(s16x8*)&h1L[bufi][t * 8] = *(const s16x8*)o;
    };

    build(0, 0);
    for (int tile = 0; tile < 12; ++tile) {
        __syncthreads();
        if (tile < 11) build(tile + 1, (tile + 1) & 1);
        const int buf = tile & 1;
        f32x4 acc0 = zero4, acc1 = zero4;      // edges 0-15 / 16-31 of tile
        #pragma unroll
        for (int kk = 0; kk < 8; ++kk) {
            s16x8 b0 = *(const s16x8*)&h1L[buf][kk * 1024 + q * 256 + ln * 8];
            s16x8 b1 = *(const s16x8*)&h1L[buf][kk * 1024 + q * 256 + 128 + ln * 8];
            acc0 = __builtin_amdgcn_mfma_f32_16x16x32_bf16(wa[kk], b0, acc0, 0, 0, 0);
            acc1 = __builtin_amdgcn_mfma_f32_16x16x32_bf16(wa[kk], b1, acc1, 0, 0, 0);
        }
        // epilogue: col=lane&15 = edge; rows = n = w*16 + q*4 + rg
        int bt = (tile >= 6) ? 1 : 0;
        int col0 = (tile - bt * 6) * 32;
        int n0 = w * 16 + q * 4;
        f32x4 b4 = *(const f32x4*)&b2L[n0];
        f32x4 m4 = *(const f32x4*)&muL[n0];
        f32x4 s4 = *(const f32x4*)&sgL[n0];
        float pmu0 = 0.f, psg0 = 0.f, pmu1 = 0.f, psg1 = 0.f;
        #pragma unroll
        for (int r = 0; r < 4; ++r) {
            float h20 = leaky(acc0[r] + b4[r]);
            float h21 = leaky(acc1[r] + b4[r]);
            pmu0 += m4[r] * h20; psg0 += s4[r] * h20;
            pmu1 += m4[r] * h21; psg1 += s4[r] * h21;
        }
        pmu0 += __shfl_xor(pmu0, 16); pmu0 += __shfl_xor(pmu0, 32);
        psg0 += __shfl_xor(psg0, 16); psg0 += __shfl_xor(psg0, 32);
        pmu1 += __shfl_xor(pmu1, 16); pmu1 += __shfl_xor(pmu1, 32);
        psg1 += __shfl_xor(psg1, 16); psg1 += __shfl_xor(psg1, 32);
        if (lane < 16) {
            atomicAdd(&mu_acc[bt * 192 + col0 + lane], pmu0);
            atomicAdd(&sg_acc[bt * 192 + col0 + lane], psg0);
            atomicAdd(&mu_acc[bt * 192 + col0 + 16 + lane], pmu1);
            atomicAdd(&sg_acc[bt * 192 + col0 + 16 + lane], psg1);
        }
    }
    __syncthreads();

    // ---- final head, both batches ----
    float lpv = 0.f;
    {
        int bt = t >> 8, i = t & 255;          // waves 0-3 bt0, 4-7 bt1, rest idle
        if (bt < 2 && i < EPB) {
            float mu = softplusf(mu_acc[bt * 192 + i] + mu_b[0]);
            float sd = softplusf(sg_acc[bt * 192 + i] + sig_b[0]);
            float z = noise[(size_t)(2 * b + bt) * EPB + i];
            out[(size_t)(2 * b + bt) * EPB + i] = mu + sd * z;
            lpv = -0.5f * z * z - logf(sd);
        }
    }
    if (w < 8) {
        #pragma unroll
        for (int off = 1; off < 64; off <<= 1) lpv += __shfl_xor(lpv, off);
        if (lane == 0) atomicAdd(&lp_acc[w >> 2], lpv);
    }
    __syncthreads();
    if (t < 2) out[M2 + 2 * b + t] = lp_acc[t] + LP_CONST;
}

// ---------------------------------------------------------------------------
extern "C" void kernel_launch(void* const* d_in, const int* in_sizes, int n_in,
                              void* d_out, int out_size, void* d_ws, size_t ws_size,
                              hipStream_t stream)
{
    const float* state  = (const float*)d_in[0];
    const float* conv_w = (const float*)d_in[1];
    const float* conv_b = (const float*)d_in[2];
    const float* lin1_w = (const float*)d_in[3];
    const float* lin1_b = (const float*)d_in[4];
    const float* lin2_w = (const float*)d_in[5];
    const float* lin2_b = (const float*)d_in[6];
    const float* mu_w   = (const float*)d_in[7];
    const float* mu_b   = (const float*)d_in[8];
    const float* sig_w  = (const float*)d_in[9];
    const float* sig_b  = (const float*)d_in[10];
    const float* noise  = (const float*)d_in[11];
    const int*   edges  = (const int*)d_in[13];
    float* out = (float*)d_out;

    char* ws = (char*)d_ws;
    short* W2bf = (short*)ws;  ws += 65536 * 2;
    short* W1bf = (short*)ws;  ws += 65536 * 2;

    prep_kernel<<<256, 256, 0, stream>>>(lin1_w, lin2_w, W2bf, W1bf);
    actor_kernel<<<NB / 2, 1024, 0, stream>>>(state, conv_w, conv_b,
                                              lin1_w, lin1_b, W1bf, W2bf,
                                              lin2_b, mu_w, mu_b, sig_w, sig_b,
                                              noise, edges, out);
}